// Round 2
// baseline (279.677 us; speedup 1.0000x reference)
//
#include <hip/hip_runtime.h>

// Problem constants (fixed by reference)
#define H    256
#define HE   64
#define NPB  512         // nodes per batch
#define NA   512         // total anchors (8 batches * 64)

// ---------------------------------------------------------------------------
// Reductions: wave shuffle + 4-partial LDS combine (2 syncs per block red)
// ---------------------------------------------------------------------------
__device__ __forceinline__ float wave_sum(float v) {
#pragma unroll
    for (int o = 32; o; o >>= 1) v += __shfl_xor(v, o, 64);
    return v;
}
__device__ __forceinline__ float wave_max(float v) {
#pragma unroll
    for (int o = 32; o; o >>= 1) v = fmaxf(v, __shfl_xor(v, o, 64));
    return v;
}
__device__ __forceinline__ float block_sum(float v, float* red4, int t) {
    v = wave_sum(v);
    if ((t & 63) == 0) red4[t >> 6] = v;
    __syncthreads();
    v = red4[0] + red4[1] + red4[2] + red4[3];
    __syncthreads();
    return v;
}
__device__ __forceinline__ float block_max(float v, float* red4, int t) {
    v = wave_max(v);
    if ((t & 63) == 0) red4[t >> 6] = v;
    __syncthreads();
    v = fmaxf(fmaxf(red4[0], red4[1]), fmaxf(red4[2], red4[3]));
    __syncthreads();
    return v;
}

// ---------------------------------------------------------------------------
// Fully fused kernel: 2 anchors per block, 256 threads.
// Factorized attention (rbf and kv never materialized):
//   s1[n]  = qW . nf[n] + q.bkv_k          (qW = Wkv_k^T q)
//   le[n]  = sum_j qe_j rbf_j(d_n)          (qe = Wkv_e_k^T q)
//   logit  = (s1+le) * (mask-1)*1e6        (exact reference semantics)
//   upd    = (Wkv_v snf + Wkv_ev rj)*inv + bkv_v,  snf = sum_n w_n nf[n]
// Then LN1, 3-layer MLP, LN2 in fp32.
// ---------------------------------------------------------------------------
__global__ void __launch_bounds__(256) fused_all(
    const float* __restrict__ anchor_x, const float* __restrict__ node_x,
    const float* __restrict__ anchor_f, const float* __restrict__ node_f,
    const float* __restrict__ node_mask,
    const float* __restrict__ Wq,  const float* __restrict__ bq,
    const float* __restrict__ Wkv, const float* __restrict__ bkv,
    const float* __restrict__ ln1_g, const float* __restrict__ ln1_b,
    const float* __restrict__ W1, const float* __restrict__ b1,
    const float* __restrict__ W2, const float* __restrict__ b2,
    const float* __restrict__ W3, const float* __restrict__ b3,
    const float* __restrict__ ln2_g, const float* __restrict__ ln2_b,
    float* __restrict__ out)
{
    const int t  = threadIdx.x;
    const int a0 = blockIdx.x * 2;
    const int b  = a0 >> 6;                 // batch (64 anchors per batch)

    __shared__ float af_s [2 * H];          // anchor features (both anchors)
    __shared__ float q_s  [2 * H];
    __shared__ float qW_s [2 * H];
    __shared__ float qe_s [2 * HE];
    __shared__ float snf_s[2 * H];
    __shared__ float rj_s [2 * HE];
    __shared__ float d10_s[2 * NPB];
    __shared__ float w_s  [2 * NPB];
    __shared__ float af1_s[2 * H];
    __shared__ float m1_s [2 * 2 * H];
    __shared__ float m2_s [2 * 2 * H];
    __shared__ float red  [256];
    __shared__ float red4 [4];

    af_s[t]     = anchor_f[(size_t)a0 * H + t];
    af_s[H + t] = anchor_f[(size_t)(a0 + 1) * H + t];
    __syncthreads();

    // ---- q = anchor_f @ Wq.T + bq (row t for both anchors, Wq row shared) ----
    {
        const float* wrow = Wq + (size_t)t * H;
        float acc0 = bq[t], acc1 = acc0;
#pragma unroll 4
        for (int c = 0; c < H; c += 4) {
            float4 w4 = *(const float4*)(wrow + c);
            acc0 += w4.x * af_s[c]     + w4.y * af_s[c + 1]
                  + w4.z * af_s[c + 2] + w4.w * af_s[c + 3];
            acc1 += w4.x * af_s[H + c]     + w4.y * af_s[H + c + 1]
                  + w4.z * af_s[H + c + 2] + w4.w * af_s[H + c + 3];
        }
        q_s[t] = acc0; q_s[H + t] = acc1;
    }
    // block_sum's internal syncs publish q_s before any cross-element read
    float bkvt  = bkv[t];
    float qbk0  = block_sum(q_s[t] * bkvt,     red4, t);
    float qbk1  = block_sum(q_s[H + t] * bkvt, red4, t);

    // ---- qW[c'] = sum_c q[c] * Wkv[c, c']  (coalesced column walk) ----
    {
        float acc0 = 0.f, acc1 = 0.f;
#pragma unroll 4
        for (int c = 0; c < H; ++c) {
            float wv = Wkv[(size_t)c * 320 + t];
            acc0 += q_s[c] * wv;
            acc1 += q_s[H + c] * wv;
        }
        qW_s[t] = acc0; qW_s[H + t] = acc1;
    }
    // ---- qe[j] = sum_c q[c] * Wkv[c, 256+j] ----
    if (t < 2 * HE) {
        int aa = t >> 6, j = t & 63;
        float acc = 0.f;
#pragma unroll 4
        for (int c = 0; c < H; ++c)
            acc += q_s[aa * H + c] * Wkv[(size_t)c * 320 + H + j];
        qe_s[t] = acc;
    }
    __syncthreads();

    float axx[2], axy[2], axz[2];
#pragma unroll
    for (int aa = 0; aa < 2; ++aa) {
        axx[aa] = anchor_x[3 * (a0 + aa) + 0];
        axy[aa] = anchor_x[3 * (a0 + aa) + 1];
        axz[aa] = anchor_x[3 * (a0 + aa) + 2];
    }

    // ---- pass 1: logits for nodes t and t+256, both anchors ----
    float lg[2][2];
#pragma unroll
    for (int nn = 0; nn < 2; ++nn) {
        int n  = t + nn * 256;
        int ng = b * NPB + n;
        float nx0 = node_x[3 * ng + 0];
        float nx1 = node_x[3 * ng + 1];
        float nx2 = node_x[3 * ng + 2];
        float mfac = (node_mask[ng] - 1.0f) * 1000000.0f;

        const float* nfr = node_f + (size_t)ng * H;
        float s1a = 0.f, s1b = 0.f;
#pragma unroll 4
        for (int c = 0; c < H; c += 4) {
            float4 v4 = *(const float4*)(nfr + c);
            s1a += v4.x * qW_s[c]     + v4.y * qW_s[c + 1]
                 + v4.z * qW_s[c + 2] + v4.w * qW_s[c + 3];
            s1b += v4.x * qW_s[H + c]     + v4.y * qW_s[H + c + 1]
                 + v4.z * qW_s[H + c + 2] + v4.w * qW_s[H + c + 3];
        }
#pragma unroll
        for (int aa = 0; aa < 2; ++aa) {
            float dx = axx[aa] - nx0 + 1e-8f;
            float dy = axy[aa] - nx1 + 1e-8f;
            float dz = axz[aa] - nx2 + 1e-8f;
            float d10 = sqrtf(dx * dx + dy * dy + dz * dz) * 0.1f;
            d10_s[aa * NPB + n] = d10;
            float le = 0.f;
#pragma unroll 8
            for (int j = 0; j < HE; ++j) {
                float u = (d10 - j * (20.0f / 63.0f)) * 3.2f;   // /sigma, sigma=0.3125
                le += qe_s[aa * HE + j] * __expf(-u * u);
            }
            float s = (aa ? s1b : s1a) + le + (aa ? qbk1 : qbk0);
            lg[aa][nn] = s * mfac;
        }
    }

    // ---- softmax over 512 nodes, per anchor ----
    float inv[2];
#pragma unroll
    for (int aa = 0; aa < 2; ++aa) {
        float gm = block_max(fmaxf(lg[aa][0], lg[aa][1]), red4, t);
        float e0 = __expf(lg[aa][0] - gm);
        float e1 = __expf(lg[aa][1] - gm);
        w_s[aa * NPB + t]       = e0;
        w_s[aa * NPB + t + 256] = e1;
        inv[aa] = 1.0f / block_sum(e0 + e1, red4, t);  // syncs publish w_s
    }

    // ---- pass 2a: snf[c'] = sum_n w_n nf[n,c']  (coalesced; skip w==0) ----
    {
        float sa = 0.f, sb = 0.f;
        const float* base = node_f + (size_t)(b * NPB) * H + t;
        for (int n = 0; n < NPB; ++n) {
            float w0 = w_s[n], w1 = w_s[NPB + n];
            if (w0 == 0.f && w1 == 0.f) continue;   // uniform branch
            float nv = base[(size_t)n * H];
            sa += w0 * nv; sb += w1 * nv;
        }
        snf_s[t] = sa; snf_s[H + t] = sb;
    }
    // ---- pass 2b: rj[j] = sum_n w_n rbf[n,j] ----
    {
        int j = t & 63, g = t >> 6;                 // 4 groups of 64 (per-wave)
        float mu = j * (20.0f / 63.0f);
        float r0 = 0.f, r1 = 0.f;
        for (int n = g; n < NPB; n += 4) {
            float w0 = w_s[n], w1 = w_s[NPB + n];
            if (w0 != 0.f) { float u = (d10_s[n] - mu) * 3.2f;        r0 += w0 * __expf(-u * u); }
            if (w1 != 0.f) { float u = (d10_s[NPB + n] - mu) * 3.2f;  r1 += w1 * __expf(-u * u); }
        }
        red[t] = r0;
        __syncthreads();
        if (t < 64) rj_s[t] = red[t] + red[t + 64] + red[t + 128] + red[t + 192];
        __syncthreads();
        red[t] = r1;
        __syncthreads();
        if (t < 64) rj_s[HE + t] = red[t] + red[t + 64] + red[t + 128] + red[t + 192];
        __syncthreads();
    }

    // ---- upd[c=t] = (Wkv_v[t,:].snf + Wkv_ev[t,:].rj)*inv + bkv_v[t] ----
    float upd[2];
    {
        const float* wrow = Wkv + (size_t)(H + t) * 320;
        float u0 = 0.f, u1 = 0.f;
#pragma unroll 4
        for (int c = 0; c < H; c += 4) {
            float4 w4 = *(const float4*)(wrow + c);
            u0 += w4.x * snf_s[c]     + w4.y * snf_s[c + 1]
                + w4.z * snf_s[c + 2] + w4.w * snf_s[c + 3];
            u1 += w4.x * snf_s[H + c]     + w4.y * snf_s[H + c + 1]
                + w4.z * snf_s[H + c + 2] + w4.w * snf_s[H + c + 3];
        }
        float e0 = 0.f, e1 = 0.f;
#pragma unroll 4
        for (int j = 0; j < HE; j += 4) {
            float4 w4 = *(const float4*)(wrow + H + j);
            e0 += w4.x * rj_s[j]     + w4.y * rj_s[j + 1]
                + w4.z * rj_s[j + 2] + w4.w * rj_s[j + 3];
            e1 += w4.x * rj_s[HE + j]     + w4.y * rj_s[HE + j + 1]
                + w4.z * rj_s[HE + j + 2] + w4.w * rj_s[HE + j + 3];
        }
        float bv = bkv[H + t];
        upd[0] = (u0 + e0) * inv[0] + bv;
        upd[1] = (u1 + e1) * inv[1] + bv;
    }

    // ---- residual + LN1 ----
    float g1 = ln1_g[t], bb1 = ln1_b[t];
    float af1r[2];
#pragma unroll
    for (int aa = 0; aa < 2; ++aa) {
        float x    = af_s[aa * H + t] + upd[aa];
        float mean = block_sum(x, red4, t) * (1.0f / 256.0f);
        float xc   = x - mean;
        float var  = block_sum(xc * xc, red4, t) * (1.0f / 256.0f);
        float v    = xc * rsqrtf(var + 1e-5f) * g1 + bb1;
        af1r[aa] = v;
        af1_s[aa * H + t] = v;
    }
    __syncthreads();

    // ---- MLP layer 1: m1 = relu(af1 @ W1.T + b1) ----
#pragma unroll
    for (int rr = 0; rr < 2; ++rr) {
        int row = t + rr * 256;
        const float* wrow = W1 + (size_t)row * H;
        float acc0 = b1[row], acc1 = acc0;
#pragma unroll 4
        for (int c = 0; c < H; c += 4) {
            float4 w4 = *(const float4*)(wrow + c);
            acc0 += w4.x * af1_s[c]     + w4.y * af1_s[c + 1]
                  + w4.z * af1_s[c + 2] + w4.w * af1_s[c + 3];
            acc1 += w4.x * af1_s[H + c]     + w4.y * af1_s[H + c + 1]
                  + w4.z * af1_s[H + c + 2] + w4.w * af1_s[H + c + 3];
        }
        m1_s[row] = fmaxf(acc0, 0.f);
        m1_s[2 * H + row] = fmaxf(acc1, 0.f);
    }
    __syncthreads();

    // ---- MLP layer 2: m2 = relu(m1 @ W2.T + b2) ----
#pragma unroll
    for (int rr = 0; rr < 2; ++rr) {
        int row = t + rr * 256;
        const float* wrow = W2 + (size_t)row * (2 * H);
        float acc0 = b2[row], acc1 = acc0;
#pragma unroll 4
        for (int c = 0; c < 2 * H; c += 4) {
            float4 w4 = *(const float4*)(wrow + c);
            acc0 += w4.x * m1_s[c]     + w4.y * m1_s[c + 1]
                  + w4.z * m1_s[c + 2] + w4.w * m1_s[c + 3];
            acc1 += w4.x * m1_s[2 * H + c]     + w4.y * m1_s[2 * H + c + 1]
                  + w4.z * m1_s[2 * H + c + 2] + w4.w * m1_s[2 * H + c + 3];
        }
        m2_s[row] = fmaxf(acc0, 0.f);
        m2_s[2 * H + row] = fmaxf(acc1, 0.f);
    }
    __syncthreads();

    // ---- MLP layer 3: m3 = m2 @ W3.T + b3 (row t) ----
    float m3[2];
    {
        const float* wrow = W3 + (size_t)t * (2 * H);
        float acc0 = b3[t], acc1 = acc0;
#pragma unroll 4
        for (int c = 0; c < 2 * H; c += 4) {
            float4 w4 = *(const float4*)(wrow + c);
            acc0 += w4.x * m2_s[c]     + w4.y * m2_s[c + 1]
                  + w4.z * m2_s[c + 2] + w4.w * m2_s[c + 3];
            acc1 += w4.x * m2_s[2 * H + c]     + w4.y * m2_s[2 * H + c + 1]
                  + w4.z * m2_s[2 * H + c + 2] + w4.w * m2_s[2 * H + c + 3];
        }
        m3[0] = acc0; m3[1] = acc1;
    }

    // ---- residual + LN2 -> out ----
    float g2 = ln2_g[t], bb2 = ln2_b[t];
#pragma unroll
    for (int aa = 0; aa < 2; ++aa) {
        float y   = af1r[aa] + m3[aa];
        float mn  = block_sum(y, red4, t) * (1.0f / 256.0f);
        float yc  = y - mn;
        float vr  = block_sum(yc * yc, red4, t) * (1.0f / 256.0f);
        out[(size_t)(a0 + aa) * H + t] = yc * rsqrtf(vr + 1e-5f) * g2 + bb2;
    }
}

// ---------------------------------------------------------------------------
extern "C" void kernel_launch(void* const* d_in, const int* in_sizes, int n_in,
                              void* d_out, int out_size, void* d_ws, size_t ws_size,
                              hipStream_t stream)
{
    const float* anchor_x  = (const float*)d_in[0];
    const float* node_x    = (const float*)d_in[1];
    const float* anchor_f  = (const float*)d_in[2];
    const float* node_f    = (const float*)d_in[3];
    // d_in[4] batch, d_in[5] anchor_batch: layouts fixed, unused
    const float* node_mask = (const float*)d_in[6];
    const float* Wq        = (const float*)d_in[7];
    const float* bq        = (const float*)d_in[8];
    const float* Wkv       = (const float*)d_in[9];
    const float* bkv       = (const float*)d_in[10];
    const float* ln1_g     = (const float*)d_in[11];
    const float* ln1_b     = (const float*)d_in[12];
    const float* W1        = (const float*)d_in[13];
    const float* b1        = (const float*)d_in[14];
    const float* W2        = (const float*)d_in[15];
    const float* b2        = (const float*)d_in[16];
    const float* W3        = (const float*)d_in[17];
    const float* b3        = (const float*)d_in[18];
    const float* ln2_g     = (const float*)d_in[19];
    const float* ln2_b     = (const float*)d_in[20];

    fused_all<<<NA / 2, 256, 0, stream>>>(
        anchor_x, node_x, anchor_f, node_f, node_mask,
        Wq, bq, Wkv, bkv, ln1_g, ln1_b,
        W1, b1, W2, b2, W3, b3, ln2_g, ln2_b,
        (float*)d_out);
}

// Round 3
// 276.382 us; speedup vs baseline: 1.0119x; 1.0119x over previous
//
#include <hip/hip_runtime.h>

// Problem constants (fixed by reference)
#define H    256
#define HE   64
#define NPB  512         // nodes per batch
#define NA   512         // total anchors (8 batches * 64)
#define MU_STEP (20.0f / 63.0f)
#define INV_SIG 3.2f     // 1/0.3125

// ---------------------------------------------------------------------------
// Reductions: wave shuffle + 4-partial LDS combine
// ---------------------------------------------------------------------------
__device__ __forceinline__ float wave_sum(float v) {
#pragma unroll
    for (int o = 32; o; o >>= 1) v += __shfl_xor(v, o, 64);
    return v;
}
__device__ __forceinline__ float wave_max(float v) {
#pragma unroll
    for (int o = 32; o; o >>= 1) v = fmaxf(v, __shfl_xor(v, o, 64));
    return v;
}
__device__ __forceinline__ float block_sum(float v, float* red4, int t) {
    v = wave_sum(v);
    if ((t & 63) == 0) red4[t >> 6] = v;
    __syncthreads();
    v = red4[0] + red4[1] + red4[2] + red4[3];
    __syncthreads();
    return v;
}
__device__ __forceinline__ float block_max(float v, float* red4, int t) {
    v = wave_max(v);
    if ((t & 63) == 0) red4[t >> 6] = v;
    __syncthreads();
    v = fmaxf(fmaxf(red4[0], red4[1]), fmaxf(red4[2], red4[3]));
    __syncthreads();
    return v;
}

// ---------------------------------------------------------------------------
// K1: per-anchor attention -> af1 (post-LN1).  512 blocks x 256 threads
//   q, qW = Wkv_k^T q, qe = Wkv_ek^T q, logits (factorized rbf), softmax,
//   winner compaction (one-hot typical), snf/rj over winners, upd, LN1.
// ---------------------------------------------------------------------------
__global__ void __launch_bounds__(256) attn_kernel(
    const float* __restrict__ anchor_x, const float* __restrict__ node_x,
    const float* __restrict__ anchor_f, const float* __restrict__ node_f,
    const float* __restrict__ node_mask,
    const float* __restrict__ Wq,  const float* __restrict__ bq,
    const float* __restrict__ Wkv, const float* __restrict__ bkv,
    const float* __restrict__ ln1_g, const float* __restrict__ ln1_b,
    float* __restrict__ af1_out)
{
    const int a = blockIdx.x;      // anchor 0..511
    const int b = a >> 6;          // batch
    const int t = threadIdx.x;

    __shared__ float af_s[H], q_s[H], qW_s[H], qe_s[HE];
    __shared__ float d10_s[NPB], w_s[NPB];
    __shared__ float snf_s[H], rj_s[HE];
    __shared__ float red[256], red4[4];
    __shared__ int   idx_s[NPB];
    __shared__ int   cnt_s;

    af_s[t] = anchor_f[(size_t)a * H + t];
    if (t == 0) cnt_s = 0;
    __syncthreads();

    // ---- q[t] = Wq[t,:] . af + bq[t] ----
    float qv;
    {
        const float* wrow = Wq + (size_t)t * H;
        float acc = bq[t];
#pragma unroll 4
        for (int c = 0; c < H; c += 4) {
            float4 w4 = *(const float4*)(wrow + c);
            acc += w4.x * af_s[c] + w4.y * af_s[c + 1]
                 + w4.z * af_s[c + 2] + w4.w * af_s[c + 3];
        }
        qv = acc;
        q_s[t] = acc;
    }
    // block_sum's syncs publish q_s
    const float qbk = block_sum(qv * bkv[t], red4, t);

    // ---- qW[t] = sum_c q[c] * Wkv[c, t]  (coalesced column walk) ----
    {
        float s = 0.f;
#pragma unroll 8
        for (int c = 0; c < H; ++c) s += q_s[c] * Wkv[(size_t)c * 320 + t];
        qW_s[t] = s;
    }
    // ---- qe[j] = sum_c q[c] * Wkv[c, 256+j]  (4-way split reduction) ----
    {
        int j = t & 63, g = t >> 6;
        float s = 0.f;
#pragma unroll 4
        for (int c = g; c < H; c += 4) s += q_s[c] * Wkv[(size_t)c * 320 + H + j];
        red[t] = s;
        __syncthreads();
        if (t < 64) qe_s[t] = red[t] + red[t + 64] + red[t + 128] + red[t + 192];
        __syncthreads();   // publishes qe_s and qW_s
    }

    const float ax0 = anchor_x[3 * a + 0];
    const float ax1 = anchor_x[3 * a + 1];
    const float ax2 = anchor_x[3 * a + 2];

    // ---- pass 1: logits for nodes t and t+256 ----
    float lg[2];
#pragma unroll
    for (int nn = 0; nn < 2; ++nn) {
        int n  = t + nn * 256;
        int ng = b * NPB + n;
        float dx = ax0 - node_x[3 * ng + 0] + 1e-8f;
        float dy = ax1 - node_x[3 * ng + 1] + 1e-8f;
        float dz = ax2 - node_x[3 * ng + 2] + 1e-8f;
        float d10 = sqrtf(dx * dx + dy * dy + dz * dz) * 0.1f;
        d10_s[n] = d10;

        float le = 0.f;
#pragma unroll 8
        for (int j = 0; j < HE; ++j) {
            float u = (d10 - j * MU_STEP) * INV_SIG;
            le += qe_s[j] * __expf(-u * u);
        }

        const float* nfr = node_f + (size_t)ng * H;
        float s1 = 0.f;
#pragma unroll 4
        for (int c = 0; c < H; c += 4) {
            float4 v4 = *(const float4*)(nfr + c);
            s1 += v4.x * qW_s[c] + v4.y * qW_s[c + 1]
                + v4.z * qW_s[c + 2] + v4.w * qW_s[c + 3];
        }
        float mfac = (node_mask[ng] - 1.0f) * 1000000.0f;
        lg[nn] = (s1 + le + qbk) * mfac;
    }

    // ---- softmax over 512 nodes ----
    float gm = block_max(fmaxf(lg[0], lg[1]), red4, t);
    float e0 = __expf(lg[0] - gm);
    float e1 = __expf(lg[1] - gm);
    w_s[t] = e0; w_s[t + 256] = e1;
    float inv = 1.0f / block_sum(e0 + e1, red4, t);  // syncs publish w_s

    // ---- compact nonzero-weight nodes (typically 1-8 of 512) ----
    if (e0 > 0.f) { int p = atomicAdd(&cnt_s, 1); idx_s[p] = t; }
    if (e1 > 0.f) { int p = atomicAdd(&cnt_s, 1); idx_s[p] = t + 256; }
    __syncthreads();
    const int cnt = cnt_s;

    // ---- snf[t] = sum_winners w_n * node_f[n, t]  (coalesced rows) ----
    {
        float s = 0.f;
        const float* base = node_f + (size_t)(b * NPB) * H + t;
        for (int i = 0; i < cnt; ++i) {
            int n = idx_s[i];
            s += w_s[n] * base[(size_t)n * H];
        }
        snf_s[t] = s;
    }
    // ---- rj[j] = sum_winners w_n * rbf[n, j] ----
    {
        int j = t & 63, g = t >> 6;
        float mu = j * MU_STEP;
        float r = 0.f;
        for (int i = g; i < cnt; i += 4) {
            int n = idx_s[i];
            float u = (d10_s[n] - mu) * INV_SIG;
            r += w_s[n] * __expf(-u * u);
        }
        red[t] = r;
        __syncthreads();
        if (t < 64) rj_s[t] = red[t] + red[t + 64] + red[t + 128] + red[t + 192];
        __syncthreads();   // publishes rj_s and snf_s
    }

    // ---- upd[t] = (Wkv_v[t,:].snf + Wkv_ev[t,:].rj) * inv + bkv_v[t] ----
    float upd;
    {
        const float* wrow = Wkv + (size_t)(H + t) * 320;
        float u = 0.f;
#pragma unroll 4
        for (int c = 0; c < H; c += 4) {
            float4 w4 = *(const float4*)(wrow + c);
            u += w4.x * snf_s[c] + w4.y * snf_s[c + 1]
               + w4.z * snf_s[c + 2] + w4.w * snf_s[c + 3];
        }
        float e = 0.f;
#pragma unroll 4
        for (int j = 0; j < HE; j += 4) {
            float4 w4 = *(const float4*)(wrow + H + j);
            e += w4.x * rj_s[j] + w4.y * rj_s[j + 1]
               + w4.z * rj_s[j + 2] + w4.w * rj_s[j + 3];
        }
        upd = (u + e) * inv + bkv[H + t];
    }

    // ---- residual + LN1 -> af1 ----
    float x    = af_s[t] + upd;
    float mean = block_sum(x, red4, t) * (1.0f / 256.0f);
    float xc   = x - mean;
    float var  = block_sum(xc * xc, red4, t) * (1.0f / 256.0f);
    af1_out[(size_t)a * H + t] = xc * rsqrtf(var + 1e-5f) * ln1_g[t] + ln1_b[t];
}

// ---------------------------------------------------------------------------
// MLP GEMM: out[512, N] = act(A[512, K] @ W[N, K]^T + bias)
// AT anchors per block staged in LDS; 256 threads = 32 cols x 8 a-groups;
// each thread: (AT/8 anchors) x 2 cols register micro-tile.
// LDS reads are wave-broadcast (<=2 distinct addrs/wave -> conflict-free).
// grid = (512/AT, N/64)
// ---------------------------------------------------------------------------
template<int AT, bool RELU>
__global__ void __launch_bounds__(256) mlp_gemm(
    const float* __restrict__ A, const float* __restrict__ W,
    const float* __restrict__ bias, float* __restrict__ out,
    int K, int N)
{
    extern __shared__ float As[];            // [AT][K]
    const int t  = threadIdx.x;
    const int a0 = blockIdx.x * AT;
    const int n0 = blockIdx.y * 64;
    const int tn = t & 31;
    const int ta = t >> 5;                   // 0..7
    constexpr int AP = AT / 8;               // anchors per thread

    for (int idx = t * 4; idx < AT * K; idx += 1024) {
        int r = idx / K, c = idx - r * K;    // K % 4 == 0, f4 stays in-row
        *(float4*)&As[r * K + c] = *(const float4*)&A[(size_t)(a0 + r) * K + c];
    }
    __syncthreads();

    const float* w0 = W + (size_t)(n0 + tn) * K;
    const float* w1 = W + (size_t)(n0 + tn + 32) * K;
    float b0v = bias[n0 + tn], b1v = bias[n0 + tn + 32];
    float acc[AP][2];
#pragma unroll
    for (int p = 0; p < AP; ++p) { acc[p][0] = b0v; acc[p][1] = b1v; }

#pragma unroll 4
    for (int k = 0; k < K; k += 4) {
        float4 wa = *(const float4*)(w0 + k);
        float4 wb = *(const float4*)(w1 + k);
#pragma unroll
        for (int p = 0; p < AP; ++p) {
            float4 av = *(const float4*)&As[(ta * AP + p) * K + k];
            acc[p][0] += av.x * wa.x + av.y * wa.y + av.z * wa.z + av.w * wa.w;
            acc[p][1] += av.x * wb.x + av.y * wb.y + av.z * wb.z + av.w * wb.w;
        }
    }

#pragma unroll
    for (int p = 0; p < AP; ++p) {
        int aRow = a0 + ta * AP + p;
        float v0 = acc[p][0], v1 = acc[p][1];
        if (RELU) { v0 = fmaxf(v0, 0.f); v1 = fmaxf(v1, 0.f); }
        out[(size_t)aRow * N + n0 + tn]      = v0;
        out[(size_t)aRow * N + n0 + tn + 32] = v1;
    }
}

// ---------------------------------------------------------------------------
// K5: residual + LN2 -> out.  512 blocks x 256 threads.
// ---------------------------------------------------------------------------
__global__ void __launch_bounds__(256) ln2_kernel(
    const float* __restrict__ y3, const float* __restrict__ af1,
    const float* __restrict__ g, const float* __restrict__ bb,
    float* __restrict__ out)
{
    __shared__ float red4[4];
    const int a = blockIdx.x, t = threadIdx.x;
    float y  = y3[(size_t)a * H + t] + af1[(size_t)a * H + t];
    float mn = block_sum(y, red4, t) * (1.0f / 256.0f);
    float yc = y - mn;
    float vr = block_sum(yc * yc, red4, t) * (1.0f / 256.0f);
    out[(size_t)a * H + t] = yc * rsqrtf(vr + 1e-5f) * g[t] + bb[t];
}

// ---------------------------------------------------------------------------
extern "C" void kernel_launch(void* const* d_in, const int* in_sizes, int n_in,
                              void* d_out, int out_size, void* d_ws, size_t ws_size,
                              hipStream_t stream)
{
    const float* anchor_x  = (const float*)d_in[0];
    const float* node_x    = (const float*)d_in[1];
    const float* anchor_f  = (const float*)d_in[2];
    const float* node_f    = (const float*)d_in[3];
    const float* node_mask = (const float*)d_in[6];
    const float* Wq        = (const float*)d_in[7];
    const float* bq        = (const float*)d_in[8];
    const float* Wkv       = (const float*)d_in[9];
    const float* bkv       = (const float*)d_in[10];
    const float* ln1_g     = (const float*)d_in[11];
    const float* ln1_b     = (const float*)d_in[12];
    const float* W1        = (const float*)d_in[13];
    const float* b1        = (const float*)d_in[14];
    const float* W2        = (const float*)d_in[15];
    const float* b2        = (const float*)d_in[16];
    const float* W3        = (const float*)d_in[17];
    const float* b3        = (const float*)d_in[18];
    const float* ln2_g     = (const float*)d_in[19];
    const float* ln2_b     = (const float*)d_in[20];

    float* af1 = (float*)d_ws;                 // 512*256
    float* m1  = af1 + (size_t)NA * H;         // 512*512
    float* m2  = m1  + (size_t)NA * 2 * H;     // 512*512
    float* y3  = m2  + (size_t)NA * 2 * H;     // 512*256  (total 3 MB)

    attn_kernel<<<NA, 256, 0, stream>>>(
        anchor_x, node_x, anchor_f, node_f, node_mask,
        Wq, bq, Wkv, bkv, ln1_g, ln1_b, af1);

    // m1 = relu(af1 @ W1^T + b1)   M=512 N=512 K=256
    mlp_gemm<16, true><<<dim3(NA / 16, 8), 256, 16 * H * 4, stream>>>(
        af1, W1, b1, m1, H, 2 * H);
    // m2 = relu(m1 @ W2^T + b2)    M=512 N=512 K=512
    mlp_gemm<16, true><<<dim3(NA / 16, 8), 256, 16 * 2 * H * 4, stream>>>(
        m1, W2, b2, m2, 2 * H, 2 * H);
    // y3 = m2 @ W3^T + b3          M=512 N=256 K=512  (AT=8 -> 256 blocks)
    mlp_gemm<8, false><<<dim3(NA / 8, 4), 256, 8 * 2 * H * 4, stream>>>(
        m2, W3, b3, y3, 2 * H, H);

    ln2_kernel<<<NA, 256, 0, stream>>>(y3, af1, ln2_g, ln2_b, (float*)d_out);
}

// Round 4
// 237.176 us; speedup vs baseline: 1.1792x; 1.1653x over previous
//
#include <hip/hip_runtime.h>

// Problem constants (fixed by reference)
#define H    256
#define HE   64
#define NPB  512         // nodes per batch
#define NA   512         // total anchors (8 batches * 64)
#define MU_STEP (20.0f / 63.0f)
#define INV_SIG 3.2f     // 1/0.3125

// ---------------------------------------------------------------------------
// Reductions: wave shuffle + 4-partial LDS combine
// ---------------------------------------------------------------------------
__device__ __forceinline__ float wave_sum(float v) {
#pragma unroll
    for (int o = 32; o; o >>= 1) v += __shfl_xor(v, o, 64);
    return v;
}
__device__ __forceinline__ float wave_max(float v) {
#pragma unroll
    for (int o = 32; o; o >>= 1) v = fmaxf(v, __shfl_xor(v, o, 64));
    return v;
}
__device__ __forceinline__ float block_sum(float v, float* red4, int t) {
    v = wave_sum(v);
    if ((t & 63) == 0) red4[t >> 6] = v;
    __syncthreads();
    v = red4[0] + red4[1] + red4[2] + red4[3];
    __syncthreads();
    return v;
}
__device__ __forceinline__ float block_max(float v, float* red4, int t) {
    v = wave_max(v);
    if ((t & 63) == 0) red4[t >> 6] = v;
    __syncthreads();
    v = fmaxf(fmaxf(red4[0], red4[1]), fmaxf(red4[2], red4[3]));
    __syncthreads();
    return v;
}

// ---------------------------------------------------------------------------
// KT: transpose W1(512x256), W2(512x512), W3(256x512) into WT layouts.
// 64x64 LDS tiles, 128 blocks x 256 threads.
// ---------------------------------------------------------------------------
__global__ void __launch_bounds__(256) transpose3_kernel(
    const float* __restrict__ W1, const float* __restrict__ W2,
    const float* __restrict__ W3,
    float* __restrict__ W1T, float* __restrict__ W2T, float* __restrict__ W3T)
{
    __shared__ float tile[64][65];
    const int t = threadIdx.x, lane = t & 63, rg = t >> 6;
    const float* src; float* dst; int R, C, tr, tc;
    int bid = blockIdx.x;
    if (bid < 32)      { src = W1; dst = W1T; R = 512; C = 256; tr = bid >> 2;  tc = bid & 3; }
    else if (bid < 96) { src = W2; dst = W2T; R = 512; C = 512; int ti = bid - 32; tr = ti >> 3; tc = ti & 7; }
    else               { src = W3; dst = W3T; R = 256; C = 512; int ti = bid - 96; tr = ti >> 3; tc = ti & 7; }

#pragma unroll
    for (int i = 0; i < 16; ++i) {
        int r = rg * 16 + i;
        tile[r][lane] = src[(size_t)(tr * 64 + r) * C + tc * 64 + lane];
    }
    __syncthreads();
#pragma unroll
    for (int i = 0; i < 16; ++i) {
        int r = rg * 16 + i;
        dst[(size_t)(tc * 64 + r) * R + tr * 64 + lane] = tile[lane][r];
    }
}

// ---------------------------------------------------------------------------
// K0: per-anchor prep: q, qbk, qW (stored transposed per-batch), qe.
// grid 512 x 256 threads.
//   qWT layout: [b][k][la]  (k=0..255, la=anchor%64) -> coalesced reads in K1
// ---------------------------------------------------------------------------
__global__ void __launch_bounds__(256) prep_kernel(
    const float* __restrict__ anchor_f,
    const float* __restrict__ Wq,  const float* __restrict__ bq,
    const float* __restrict__ Wkv, const float* __restrict__ bkv,
    float* __restrict__ qWT, float* __restrict__ qe_ws, float* __restrict__ qbk_ws)
{
    const int a = blockIdx.x, b = a >> 6, la = a & 63, t = threadIdx.x;
    __shared__ float af_s[H], q_s[H], red[256], red4[4];

    af_s[t] = anchor_f[(size_t)a * H + t];
    __syncthreads();

    // q[t] = Wq[t,:] . af + bq[t]
    float qv;
    {
        const float* wrow = Wq + (size_t)t * H;
        float acc = bq[t];
#pragma unroll 4
        for (int c = 0; c < H; c += 4) {
            float4 w4 = *(const float4*)(wrow + c);
            acc += w4.x * af_s[c] + w4.y * af_s[c + 1]
                 + w4.z * af_s[c + 2] + w4.w * af_s[c + 3];
        }
        qv = acc; q_s[t] = acc;
    }
    float qbk = block_sum(qv * bkv[t], red4, t);   // syncs publish q_s

    // qW[t] = sum_c q[c] * Wkv[c, t]  (coalesced column walk)
    {
        float s = 0.f;
#pragma unroll 8
        for (int c = 0; c < H; ++c) s += q_s[c] * Wkv[(size_t)c * 320 + t];
        qWT[((size_t)b * H + t) * 64 + la] = s;
    }
    // qe[j] = sum_c q[c] * Wkv[c, 256+j]
    {
        int j = t & 63, g = t >> 6;
        float s = 0.f;
#pragma unroll 4
        for (int c = g; c < H; c += 4) s += q_s[c] * Wkv[(size_t)c * 320 + H + j];
        red[t] = s;
        __syncthreads();
        if (t < 64) qe_ws[(size_t)a * 64 + t] = red[t] + red[t + 64] + red[t + 128] + red[t + 192];
    }
    if (t == 0) qbk_ws[a] = qbk;
}

// ---------------------------------------------------------------------------
// K1: logits. grid 512 = (batch, 8-node chunk); 256 thr = 64 anchors x 4 node-grps.
// Each thread: 2 nodes for its anchor. node_f staged once in LDS (read once
// total, not 64x). qWT loads coalesced; LDS reads broadcast.
//   lgT layout: [b][n][la]
// ---------------------------------------------------------------------------
__global__ void __launch_bounds__(256) logits_kernel(
    const float* __restrict__ anchor_x, const float* __restrict__ node_x,
    const float* __restrict__ node_f,   const float* __restrict__ node_mask,
    const float* __restrict__ qWT, const float* __restrict__ qe_ws,
    const float* __restrict__ qbk_ws, float* __restrict__ lgT)
{
    const int bid = blockIdx.x, b = bid >> 6, chunk = bid & 63, n0 = chunk * 8;
    const int t = threadIdx.x, la = t & 63, ng = t >> 6;

    __shared__ float nf_s[8 * H];        // 8 rows, contiguous
    __shared__ float qe_s[64 * 65];      // [j][la], padded
    __shared__ float nx_s[8][4];
    __shared__ float mf_s[8];

    // stage node_f rows (8*256 floats, globally contiguous)
    {
        const float4* src = (const float4*)(node_f + ((size_t)b * NPB + n0) * H);
        float4* dst = (float4*)nf_s;
        dst[t] = src[t];
        dst[t + 256] = src[t + 256];
    }
    // stage qe transposed: qe_s[j][la]  (write banks conflict-free via 65 pad)
#pragma unroll
    for (int i = 0; i < 16; ++i) {
        int e = t + i * 256;                       // e = la_src*64 + j
        qe_s[(e & 63) * 65 + (e >> 6)] = qe_ws[(size_t)b * 4096 + e];
    }
    if (t < 8) {
        mf_s[t] = (node_mask[b * NPB + n0 + t] - 1.0f) * 1000000.0f;
        nx_s[t][0] = node_x[3 * (b * NPB + n0 + t) + 0];
        nx_s[t][1] = node_x[3 * (b * NPB + n0 + t) + 1];
        nx_s[t][2] = node_x[3 * (b * NPB + n0 + t) + 2];
    }
    __syncthreads();

    const float ax0 = anchor_x[3 * (b * 64 + la) + 0];
    const float ax1 = anchor_x[3 * (b * 64 + la) + 1];
    const float ax2 = anchor_x[3 * (b * 64 + la) + 2];
    const float qbk = qbk_ws[b * 64 + la];

    // s1 for two nodes (ng, ng+4): one coalesced qWT load feeds both
    float acc0 = 0.f, acc1 = 0.f;
    {
        const float* qwcol = qWT + (size_t)b * H * 64 + la;
        const float* r0 = nf_s + ng * H;
        const float* r1 = nf_s + (ng + 4) * H;
#pragma unroll 8
        for (int k = 0; k < H; ++k) {
            float w = qwcol[(size_t)k * 64];
            acc0 += w * r0[k];
            acc1 += w * r1[k];
        }
    }
#pragma unroll
    for (int nn = 0; nn < 2; ++nn) {
        int nl = ng + nn * 4;
        float dx = ax0 - nx_s[nl][0] + 1e-8f;
        float dy = ax1 - nx_s[nl][1] + 1e-8f;
        float dz = ax2 - nx_s[nl][2] + 1e-8f;
        float d10 = sqrtf(dx * dx + dy * dy + dz * dz) * 0.1f;
        float le = 0.f;
#pragma unroll 8
        for (int j = 0; j < HE; ++j) {
            float u = (d10 - j * MU_STEP) * INV_SIG;
            le += qe_s[j * 65 + la] * __expf(-u * u);
        }
        float lg = ((nn ? acc1 : acc0) + le + qbk) * mf_s[nl];
        lgT[((size_t)b * NPB + n0 + nl) * 64 + la] = lg;
    }
}

// ---------------------------------------------------------------------------
// K2: per-anchor softmax + winner compaction + upd + LN1 -> af1.
// grid 512 x 256 threads.
// ---------------------------------------------------------------------------
__global__ void __launch_bounds__(256) reduce_kernel(
    const float* __restrict__ anchor_x, const float* __restrict__ node_x,
    const float* __restrict__ anchor_f, const float* __restrict__ node_f,
    const float* __restrict__ lgT,
    const float* __restrict__ Wkv, const float* __restrict__ bkv,
    const float* __restrict__ ln1_g, const float* __restrict__ ln1_b,
    float* __restrict__ af1_out)
{
    const int a = blockIdx.x, b = a >> 6, la = a & 63, t = threadIdx.x;
    __shared__ float w_s[NPB], snf_s[H], rj_s[HE], red[256], red4[4];
    __shared__ int idx_s[NPB];
    __shared__ int cnt_s;
    if (t == 0) cnt_s = 0;

    float lg0 = lgT[((size_t)b * NPB + t) * 64 + la];
    float lg1 = lgT[((size_t)b * NPB + t + 256) * 64 + la];

    float gm = block_max(fmaxf(lg0, lg1), red4, t);   // also publishes cnt_s=0
    float e0 = __expf(lg0 - gm);
    float e1 = __expf(lg1 - gm);
    w_s[t] = e0; w_s[t + 256] = e1;
    float inv = 1.0f / block_sum(e0 + e1, red4, t);   // syncs publish w_s

    if (e0 > 0.f) { int p = atomicAdd(&cnt_s, 1); idx_s[p] = t; }
    if (e1 > 0.f) { int p = atomicAdd(&cnt_s, 1); idx_s[p] = t + 256; }
    __syncthreads();
    const int cnt = cnt_s;

    // snf[t] = sum_winners w_n * node_f[n, t]
    {
        float s = 0.f;
        const float* base = node_f + (size_t)(b * NPB) * H + t;
        for (int i = 0; i < cnt; ++i) {
            int n = idx_s[i];
            s += w_s[n] * base[(size_t)n * H];
        }
        snf_s[t] = s;
    }
    // rj[j] = sum_winners w_n * rbf[n, j]   (d10 recomputed, same fp order as K1)
    {
        const float ax0 = anchor_x[3 * a + 0];
        const float ax1 = anchor_x[3 * a + 1];
        const float ax2 = anchor_x[3 * a + 2];
        int j = t & 63, g = t >> 6;
        float mu = j * MU_STEP;
        float r = 0.f;
        for (int i = g; i < cnt; i += 4) {
            int n = idx_s[i];
            int ngi = b * NPB + n;
            float dx = ax0 - node_x[3 * ngi + 0] + 1e-8f;
            float dy = ax1 - node_x[3 * ngi + 1] + 1e-8f;
            float dz = ax2 - node_x[3 * ngi + 2] + 1e-8f;
            float d10 = sqrtf(dx * dx + dy * dy + dz * dz) * 0.1f;
            float u = (d10 - mu) * INV_SIG;
            r += w_s[n] * __expf(-u * u);
        }
        red[t] = r;
        __syncthreads();
        if (t < 64) rj_s[t] = red[t] + red[t + 64] + red[t + 128] + red[t + 192];
        __syncthreads();
    }

    // upd[t] = (Wkv_v[t,:].snf + Wkv_ev[t,:].rj) * inv + bkv_v[t]
    float upd;
    {
        const float* wrow = Wkv + (size_t)(H + t) * 320;
        float u = 0.f;
#pragma unroll 4
        for (int c = 0; c < H; c += 4) {
            float4 w4 = *(const float4*)(wrow + c);
            u += w4.x * snf_s[c] + w4.y * snf_s[c + 1]
               + w4.z * snf_s[c + 2] + w4.w * snf_s[c + 3];
        }
        float e = 0.f;
#pragma unroll 4
        for (int j = 0; j < HE; j += 4) {
            float4 w4 = *(const float4*)(wrow + H + j);
            e += w4.x * rj_s[j] + w4.y * rj_s[j + 1]
               + w4.z * rj_s[j + 2] + w4.w * rj_s[j + 3];
        }
        upd = (u + e) * inv + bkv[H + t];
    }

    // residual + LN1
    float x    = anchor_f[(size_t)a * H + t] + upd;
    float mean = block_sum(x, red4, t) * (1.0f / 256.0f);
    float xc   = x - mean;
    float var  = block_sum(xc * xc, red4, t) * (1.0f / 256.0f);
    af1_out[(size_t)a * H + t] = xc * rsqrtf(var + 1e-5f) * ln1_g[t] + ln1_b[t];
}

// ---------------------------------------------------------------------------
// MLP GEMM with transposed weights: out[a][n] = act(sum_k A[a][k]*WT[k][n] + b[n])
// Block: 16 anchors x 64 cols, 512 threads (8 waves), 2 outputs/thread.
// WT loads coalesced 256B/wave, one load feeds 2 FMAs; A-tile LDS broadcast.
// grid = (M/16, N/64)
// ---------------------------------------------------------------------------
template<bool RELU>
__global__ void __launch_bounds__(512) mlp_gemm(
    const float* __restrict__ A, const float* __restrict__ WT,
    const float* __restrict__ bias, float* __restrict__ out,
    int K, int N)
{
    extern __shared__ float As[];                    // [16][K]
    const int t  = threadIdx.x;
    const int tn = t & 63, tg = t >> 6;              // col lane, anchor group 0..7
    const int a0 = blockIdx.x * 16;
    const int n  = blockIdx.y * 64 + tn;

    {
        const float4* src = (const float4*)(A + (size_t)a0 * K);
        float4* dst = (float4*)As;
        for (int p = t; p < 4 * K; p += 512) dst[p] = src[p];
    }
    __syncthreads();

    float acc0 = bias[n], acc1 = acc0;
    const float* w = WT + n;
    const float* r0 = As + (size_t)tg * K;
    const float* r1 = As + (size_t)(tg + 8) * K;
#pragma unroll 8
    for (int k = 0; k < K; ++k) {
        float wv = w[(size_t)k * N];
        acc0 += r0[k] * wv;
        acc1 += r1[k] * wv;
    }
    if (RELU) { acc0 = fmaxf(acc0, 0.f); acc1 = fmaxf(acc1, 0.f); }
    out[(size_t)(a0 + tg) * N + n]     = acc0;
    out[(size_t)(a0 + tg + 8) * N + n] = acc1;
}

// ---------------------------------------------------------------------------
// K6: residual + LN2 -> out. 512 blocks x 256 threads.
// ---------------------------------------------------------------------------
__global__ void __launch_bounds__(256) ln2_kernel(
    const float* __restrict__ y3, const float* __restrict__ af1,
    const float* __restrict__ g, const float* __restrict__ bb,
    float* __restrict__ out)
{
    __shared__ float red4[4];
    const int a = blockIdx.x, t = threadIdx.x;
    float y  = y3[(size_t)a * H + t] + af1[(size_t)a * H + t];
    float mn = block_sum(y, red4, t) * (1.0f / 256.0f);
    float yc = y - mn;
    float vr = block_sum(yc * yc, red4, t) * (1.0f / 256.0f);
    out[(size_t)a * H + t] = yc * rsqrtf(vr + 1e-5f) * g[t] + bb[t];
}

// ---------------------------------------------------------------------------
extern "C" void kernel_launch(void* const* d_in, const int* in_sizes, int n_in,
                              void* d_out, int out_size, void* d_ws, size_t ws_size,
                              hipStream_t stream)
{
    const float* anchor_x  = (const float*)d_in[0];
    const float* node_x    = (const float*)d_in[1];
    const float* anchor_f  = (const float*)d_in[2];
    const float* node_f    = (const float*)d_in[3];
    const float* node_mask = (const float*)d_in[6];
    const float* Wq        = (const float*)d_in[7];
    const float* bq        = (const float*)d_in[8];
    const float* Wkv       = (const float*)d_in[9];
    const float* bkv       = (const float*)d_in[10];
    const float* ln1_g     = (const float*)d_in[11];
    const float* ln1_b     = (const float*)d_in[12];
    const float* W1        = (const float*)d_in[13];
    const float* b1        = (const float*)d_in[14];
    const float* W2        = (const float*)d_in[15];
    const float* b2        = (const float*)d_in[16];
    const float* W3        = (const float*)d_in[17];
    const float* b3        = (const float*)d_in[18];
    const float* ln2_g     = (const float*)d_in[19];
    const float* ln2_b     = (const float*)d_in[20];

    float* ws     = (float*)d_ws;
    float* qWT    = ws;                 // 8*256*64    = 131072
    float* qe_ws  = qWT    + 131072;    // 512*64      = 32768
    float* qbk_ws = qe_ws  + 32768;     // 512 (pad 1024)
    float* lgT    = qbk_ws + 1024;      // 8*512*64    = 262144
    float* af1    = lgT    + 262144;    // 512*256     = 131072
    float* m1     = af1    + 131072;    // 512*512     = 262144
    float* m2     = m1     + 262144;    // 512*512     = 262144
    float* y3     = m2     + 262144;    // 512*256     = 131072
    float* W1T    = y3     + 131072;    // 256*512     = 131072
    float* W2T    = W1T    + 131072;    // 512*512     = 262144
    float* W3T    = W2T    + 262144;    // 512*256     = 131072
    // total ~6.95 MB

    transpose3_kernel<<<128, 256, 0, stream>>>(W1, W2, W3, W1T, W2T, W3T);

    prep_kernel<<<NA, 256, 0, stream>>>(anchor_f, Wq, bq, Wkv, bkv,
                                        qWT, qe_ws, qbk_ws);

    logits_kernel<<<512, 256, 0, stream>>>(anchor_x, node_x, node_f, node_mask,
                                           qWT, qe_ws, qbk_ws, lgT);

    reduce_kernel<<<NA, 256, 0, stream>>>(anchor_x, node_x, anchor_f, node_f,
                                          lgT, Wkv, bkv, ln1_g, ln1_b, af1);

    mlp_gemm<true><<<dim3(32, 8), 512, 16 * 256 * 4, stream>>>(af1, W1T, b1, m1, 256, 512);
    mlp_gemm<true><<<dim3(32, 8), 512, 16 * 512 * 4, stream>>>(m1,  W2T, b2, m2, 512, 512);
    mlp_gemm<false><<<dim3(32, 4), 512, 16 * 512 * 4, stream>>>(m2, W3T, b3, y3, 512, 256);

    ln2_kernel<<<NA, 256, 0, stream>>>(y3, af1, ln2_g, ln2_b, (float*)d_out);
}